// Round 2
// baseline (543.975 us; speedup 1.0000x reference)
//
#include <hip/hip_runtime.h>
#include <hip/hip_bf16.h>
#include <stdint.h>

// Problem constants (B, N, E, D) = (32, 4096, 8192, 128)
// ALL float tensors are fp32 (per reference); connectivity is int32.
// Round-1 NaN post-mortem: reading fp32 data as bf16 produces Inf/NaN
// (low mantissa halves hit exponent 0xFF with P~2^-8) -> inputs are fp32.
#define BB 32
#define NN 4096
#define EE 8192
#define DD 128
#define MM (BB * NN)        // 131072 rows
#define THREE_D (3 * DD)    // 384

typedef __bf16 bf16x8 __attribute__((ext_vector_type(8)));
typedef float  f32x4  __attribute__((ext_vector_type(4)));
typedef float  f32x2  __attribute__((ext_vector_type(2)));

// ws layout:
//   [0, AGG_BYTES)              : aggregated messages, fp32, (B*N, D)   64 MiB
//   [AGG_BYTES, +2*384*128*2B)  : transposed weights bf16 [mat][col(384)][k(128)]
#define AGG_BYTES ((size_t)MM * DD * 4)
#define WT_ELEMS  (2 * THREE_D * DD)      // 98304

// ---------------------------------------------------------------------------
// Kernel 1: transpose + fp32->bf16 convert both weight matrices (D,3D)->(3D,D)
// so the MFMA B-fragment (8 consecutive k for fixed col) is one 16-B load.
// ---------------------------------------------------------------------------
__global__ void transpose_weights(const float* __restrict__ w0,
                                  const float* __restrict__ w1,
                                  __bf16* __restrict__ wt) {
    int tid = blockIdx.x * blockDim.x + threadIdx.x;   // 0 .. 98303
    int mat = tid / (THREE_D * DD);
    int rem = tid % (THREE_D * DD);
    int col = rem / DD;
    int k   = rem % DD;
    const float* src = mat ? w1 : w0;
    wt[tid] = (__bf16)src[k * THREE_D + col];
}

// ---------------------------------------------------------------------------
// Kernel 2: segment-sum scatter. One 64-lane wave per edge, 2 fp32 elements
// per lane, safe fp32 atomics (avg multiplicity E/N = 2 -> low contention).
// ---------------------------------------------------------------------------
__global__ void scatter_messages(const float* __restrict__ messages,
                                 const int* __restrict__ conn,
                                 float* __restrict__ agg) {
    int edge = blockIdx.x * 4 + (threadIdx.x >> 6);    // 4 edges per 256-thr block
    int lane = threadIdx.x & 63;
    int b    = edge / EE;
    int tgt  = conn[edge * 2 + 1];                     // connectivity[...,1]
    f32x2 v = *(const f32x2*)(messages + (size_t)edge * DD + lane * 2);
    float* dst = agg + ((size_t)(b * NN + tgt)) * DD + lane * 2;
    atomicAdd(dst,     v[0]);
    atomicAdd(dst + 1, v[1]);
}

// ---------------------------------------------------------------------------
// Kernel 3: fused dual-GEMM + GRU gates.
//   matrix_x = agg @ W0 + bias[0]   (agg fp32 -> bf16 in-flight)
//   matrix_h = h   @ W1 + bias[1]   (h   fp32 -> bf16 in-flight)
//   z = sig(xz+rz); r = sig(xr+rr); hh = tanh(xh + r*rh)
//   out = z*h + (1-z)*hh            (h term in full fp32)
// Block: 256 threads = 4 waves; 128 rows/block; wave owns 32 rows (2 M-tiles
// of 16). A-fragments register-resident. 8 gate-column groups of 16; per
// group 12 accum tiles (2 mt x 3 parts x 2 matrices), K=128 in 4 MFMA steps.
// No LDS, no barriers. Weights (192 KB bf16) stream from L2.
// MFMA layouts (gfx950, verified): A[m=lane&15][k=quad*8+j],
// B[k=quad*8+j][n=lane&15], C/D: col=lane&15, row=quad*4+reg.
// ---------------------------------------------------------------------------
__launch_bounds__(256)
__global__ void gru_gemm(const float* __restrict__ agg,
                         const float* __restrict__ h_in,
                         const __bf16* __restrict__ wt,
                         const float* __restrict__ bias,
                         float* __restrict__ out) {
    const int wave = threadIdx.x >> 6;
    const int lane = threadIdx.x & 63;
    const int quad = lane >> 4;
    const int l16  = lane & 15;
    const int row0 = blockIdx.x * 128 + wave * 32;     // wave's first row

    // A fragments: [mat][mt][ko]; mat 0 = aggregated (x path), 1 = h (r path)
    bf16x8 afrag[2][2][4];
    for (int mt = 0; mt < 2; ++mt) {
        int r = row0 + mt * 16 + l16;
        const float* grow = agg  + (size_t)r * DD;
        const float* hrow = h_in + (size_t)r * DD;
        for (int ko = 0; ko < 4; ++ko) {
            int k = ko * 32 + quad * 8;
            f32x4 g0 = *(const f32x4*)(grow + k);
            f32x4 g1 = *(const f32x4*)(grow + k + 4);
            f32x4 h0 = *(const f32x4*)(hrow + k);
            f32x4 h1 = *(const f32x4*)(hrow + k + 4);
            bf16x8 ag, hg;
            for (int i = 0; i < 4; ++i) {
                ag[i]     = (__bf16)g0[i];
                ag[i + 4] = (__bf16)g1[i];
                hg[i]     = (__bf16)h0[i];
                hg[i + 4] = (__bf16)h1[i];
            }
            afrag[0][mt][ko] = ag;
            afrag[1][mt][ko] = hg;
        }
    }

    for (int g = 0; g < 8; ++g) {
        f32x4 acc[2][3][2];                            // [mt][part z/r/h][mat x/h]
        for (int mt = 0; mt < 2; ++mt)
            for (int p = 0; p < 3; ++p)
                for (int m = 0; m < 2; ++m)
                    acc[mt][p][m] = (f32x4){0.f, 0.f, 0.f, 0.f};

        for (int ko = 0; ko < 4; ++ko) {
            for (int p = 0; p < 3; ++p) {
                for (int m = 0; m < 2; ++m) {
                    int col = p * 128 + g * 16 + l16;
                    bf16x8 bfrag = *(const bf16x8*)(wt + ((size_t)m * THREE_D + col) * DD
                                                       + ko * 32 + quad * 8);
                    for (int mt = 0; mt < 2; ++mt)
                        acc[mt][p][m] = __builtin_amdgcn_mfma_f32_16x16x32_bf16(
                            afrag[m][mt][ko], bfrag, acc[mt][p][m], 0, 0, 0);
                }
            }
        }

        // Epilogue for this 16-wide gate-column group
        int j = g * 16 + l16;                          // gate index 0..127
        float b0z = bias[j];
        float b0r = bias[DD + j];
        float b0h = bias[2 * DD + j];
        float b1z = bias[THREE_D + j];
        float b1r = bias[THREE_D + DD + j];
        float b1h = bias[THREE_D + 2 * DD + j];

        for (int mt = 0; mt < 2; ++mt) {
            for (int rr = 0; rr < 4; ++rr) {
                int row = row0 + mt * 16 + quad * 4 + rr;
                float xz = acc[mt][0][0][rr] + b0z;
                float rz = acc[mt][0][1][rr] + b1z;
                float xr = acc[mt][1][0][rr] + b0r;
                float rrg = acc[mt][1][1][rr] + b1r;
                float xh = acc[mt][2][0][rr] + b0h;
                float rh = acc[mt][2][1][rr] + b1h;
                float z  = 1.f / (1.f + __expf(-(xz + rz)));
                float rg = 1.f / (1.f + __expf(-(xr + rrg)));
                float pre = xh + rg * rh;
                float hh = 2.f / (1.f + __expf(-2.f * pre)) - 1.f;   // tanh(pre)
                float hold = h_in[(size_t)row * DD + j];
                float o = z * hold + (1.f - z) * hh;
                out[(size_t)row * DD + j] = o;
            }
        }
    }
}

// ---------------------------------------------------------------------------
extern "C" void kernel_launch(void* const* d_in, const int* in_sizes, int n_in,
                              void* d_out, int out_size, void* d_ws, size_t ws_size,
                              hipStream_t stream) {
    const float* atom_state = (const float*)d_in[0];
    const float* messages   = (const float*)d_in[1];
    const int*   conn       = (const int*)d_in[2];
    const float* w0         = (const float*)d_in[3];
    const float* w1         = (const float*)d_in[4];
    const float* bias       = (const float*)d_in[5];
    float* out = (float*)d_out;

    float*  agg = (float*)d_ws;
    __bf16* wt  = (__bf16*)((char*)d_ws + AGG_BYTES);

    hipMemsetAsync(agg, 0, AGG_BYTES, stream);
    transpose_weights<<<WT_ELEMS / 256, 256, 0, stream>>>(w0, w1, wt);
    scatter_messages<<<(BB * EE) / 4, 256, 0, stream>>>(messages, conn, agg);
    gru_gemm<<<MM / 128, 256, 0, stream>>>(agg, atom_state, wt, bias, out);
}

// Round 3
// 405.063 us; speedup vs baseline: 1.3429x; 1.3429x over previous
//
#include <hip/hip_runtime.h>
#include <hip/hip_bf16.h>
#include <stdint.h>

// Problem constants (B, N, E, D) = (32, 4096, 8192, 128); all float io fp32.
// R2 post-mortem: atomic scatter 220us @1.5TB/s (atomic-bound), gemm ~310us
// (scattered 256B-stride B-fragment loads thrash L1). R3: CSR gather (no
// atomics, agg stored bf16) + LDS-staged weights (double-buffered).
#define BB 32
#define NN 4096
#define EE 8192
#define DD 128
#define MM (BB * NN)        // 131072 rows
#define THREE_D (3 * DD)    // 384
#define CAP 32              // bucket capacity; deg~Poisson(2), P(deg>31)<1e-25

typedef __bf16 bf16x8 __attribute__((ext_vector_type(8)));
typedef __bf16 bf16x2 __attribute__((ext_vector_type(2)));
typedef float  f32x4  __attribute__((ext_vector_type(4)));
typedef float  f32x2  __attribute__((ext_vector_type(2)));

// ws layout
#define AGG_BYTES ((size_t)MM * DD * 2)           // 32 MiB, bf16 aggregate
#define WT_OFF    AGG_BYTES
#define WT_BYTES  ((size_t)2 * THREE_D * DD * 2)  // 192 KiB, bf16 [mat][col][k]
#define CNT_OFF   (WT_OFF + WT_BYTES)
#define CNT_BYTES ((size_t)MM * 4)                // 512 KiB
#define BKT_OFF   (CNT_OFF + CNT_BYTES)           // 16 MiB edge-id buckets

// ---------------------------------------------------------------------------
// Kernel 1: transpose + fp32->bf16 both weight matrices (D,3D)->(3D,D).
// ---------------------------------------------------------------------------
__global__ void transpose_weights(const float* __restrict__ w0,
                                  const float* __restrict__ w1,
                                  __bf16* __restrict__ wt) {
    int tid = blockIdx.x * blockDim.x + threadIdx.x;   // 0 .. 98303
    int mat = tid / (THREE_D * DD);
    int rem = tid % (THREE_D * DD);
    int col = rem / DD;
    int k   = rem % DD;
    const float* src = mat ? w1 : w0;
    wt[tid] = (__bf16)src[k * THREE_D + col];
}

// ---------------------------------------------------------------------------
// Kernel 2: build CSR buckets. One thread per edge; atomicAdd on 131072
// counters only (cheap), store global edge id.
// ---------------------------------------------------------------------------
__global__ void scatter_ids(const int* __restrict__ conn,
                            int* __restrict__ counts,
                            int* __restrict__ bucket) {
    int e = blockIdx.x * 256 + threadIdx.x;            // 0 .. B*E-1
    int b = e >> 13;                                   // e / EE
    int tgt = conn[e * 2 + 1];
    int node = b * NN + tgt;
    int pos = atomicAdd(&counts[node], 1);
    if (pos < CAP) bucket[node * CAP + pos] = e;
}

// ---------------------------------------------------------------------------
// Kernel 3: gather-aggregate. One wave per node; sum message rows (avg deg 2)
// with coalesced float2 loads; write agg as bf16 (feeds MFMA A directly).
// ---------------------------------------------------------------------------
__global__ void gather_messages(const float* __restrict__ messages,
                                const int* __restrict__ counts,
                                const int* __restrict__ bucket,
                                __bf16* __restrict__ agg) {
    int node = blockIdx.x * 4 + (threadIdx.x >> 6);
    int lane = threadIdx.x & 63;
    int cnt = counts[node];
    if (cnt > CAP) cnt = CAP;
    float a0 = 0.f, a1 = 0.f;
    for (int i = 0; i < cnt; ++i) {
        int e = bucket[node * CAP + i];
        f32x2 v = *(const f32x2*)(messages + (size_t)e * DD + lane * 2);
        a0 += v[0];
        a1 += v[1];
    }
    bf16x2 o;
    o[0] = (__bf16)a0;
    o[1] = (__bf16)a1;
    *(bf16x2*)(agg + (size_t)node * DD + lane * 2) = o;
}

// ---------------------------------------------------------------------------
// Kernel 4: fused dual-GEMM + GRU gates, weights LDS-staged.
// Block: 256 thr = 4 waves, 128 rows; wave owns 2 M-tiles of 16 rows.
// g-loop over 8 gate-column groups of 16; per g the block stages 24 KB of
// weights (6 slices of [16 col][128 k], col stride padded to 136 elems ->
// 2-way LDS conflicts only) double-buffered; 24 ds_read_b128 + 48 MFMA per g.
// MFMA layouts (gfx950, verified): A[m=lane&15][k=quad*8+j],
// B[k=quad*8+j][n=lane&15], C/D: col=lane&15, row=quad*4+reg.
// ---------------------------------------------------------------------------
#define COLP 136   // padded col stride in elements (272 B)
__launch_bounds__(256)
__global__ void gru_gemm(const __bf16* __restrict__ agg,
                         const float* __restrict__ h_in,
                         const __bf16* __restrict__ wt,
                         const float* __restrict__ bias,
                         float* __restrict__ out) {
    const int wave = threadIdx.x >> 6;
    const int lane = threadIdx.x & 63;
    const int quad = lane >> 4;
    const int l16  = lane & 15;
    const int row0 = blockIdx.x * 128 + wave * 32;

    __shared__ __bf16 lb[2][6 * 16 * COLP];            // 2 x 25.5 KiB

    // A fragments: [mat][mt][ko]; mat 0 = aggregated bf16, 1 = h fp32->bf16
    bf16x8 afrag[2][2][4];
    for (int mt = 0; mt < 2; ++mt) {
        int r = row0 + mt * 16 + l16;
        const __bf16* arow = agg  + (size_t)r * DD;
        const float*  hrow = h_in + (size_t)r * DD;
        for (int ko = 0; ko < 4; ++ko) {
            int k = ko * 32 + quad * 8;
            afrag[0][mt][ko] = *(const bf16x8*)(arow + k);
            f32x4 h0 = *(const f32x4*)(hrow + k);
            f32x4 h1 = *(const f32x4*)(hrow + k + 4);
            bf16x8 hg;
            for (int i = 0; i < 4; ++i) {
                hg[i]     = (__bf16)h0[i];
                hg[i + 4] = (__bf16)h1[i];
            }
            afrag[1][mt][ko] = hg;
        }
    }

    // cooperative stage of gate-group g's weights into buffer buf
    auto stage = [&](int g, int buf) {
        for (int c = threadIdx.x; c < 1536; c += 256) {
            int slice = c >> 8;                        // m*3+p, 0..5
            int rem   = c & 255;
            int col   = rem >> 4;                      // 0..15
            int ch    = rem & 15;                      // 16-B chunk, 0..15
            int m = slice / 3, p = slice % 3;
            bf16x8 v = *(const bf16x8*)(wt
                + ((size_t)(m * THREE_D + p * 128 + g * 16 + col)) * DD + ch * 8);
            *(bf16x8*)&lb[buf][(slice * 16 + col) * COLP + ch * 8] = v;
        }
    };

    stage(0, 0);
    for (int g = 0; g < 8; ++g) {
        __syncthreads();                               // stage(g) visible
        if (g < 7) stage(g + 1, (g + 1) & 1);
        int buf = g & 1;

        f32x4 acc[2][3][2];                            // [mt][part z/r/h][mat]
        for (int mt = 0; mt < 2; ++mt)
            for (int p = 0; p < 3; ++p)
                for (int m = 0; m < 2; ++m)
                    acc[mt][p][m] = (f32x4){0.f, 0.f, 0.f, 0.f};

        for (int ko = 0; ko < 4; ++ko) {
            for (int p = 0; p < 3; ++p) {
                for (int m = 0; m < 2; ++m) {
                    bf16x8 bfrag = *(const bf16x8*)&lb[buf]
                        [((m * 3 + p) * 16 + l16) * COLP + ko * 32 + quad * 8];
                    for (int mt = 0; mt < 2; ++mt)
                        acc[mt][p][m] = __builtin_amdgcn_mfma_f32_16x16x32_bf16(
                            afrag[m][mt][ko], bfrag, acc[mt][p][m], 0, 0, 0);
                }
            }
        }

        int j = g * 16 + l16;                          // gate index 0..127
        float b0z = bias[j];
        float b0r = bias[DD + j];
        float b0h = bias[2 * DD + j];
        float b1z = bias[THREE_D + j];
        float b1r = bias[THREE_D + DD + j];
        float b1h = bias[THREE_D + 2 * DD + j];

        for (int mt = 0; mt < 2; ++mt) {
            for (int rr = 0; rr < 4; ++rr) {
                int row = row0 + mt * 16 + quad * 4 + rr;
                float xz = acc[mt][0][0][rr] + b0z;
                float rz = acc[mt][0][1][rr] + b1z;
                float xr = acc[mt][1][0][rr] + b0r;
                float rrg = acc[mt][1][1][rr] + b1r;
                float xh = acc[mt][2][0][rr] + b0h;
                float rh = acc[mt][2][1][rr] + b1h;
                float z  = 1.f / (1.f + __expf(-(xz + rz)));
                float rg = 1.f / (1.f + __expf(-(xr + rrg)));
                float pre = xh + rg * rh;
                float hh = 2.f / (1.f + __expf(-2.f * pre)) - 1.f;   // tanh
                float hold = h_in[(size_t)row * DD + j];
                float o = z * hold + (1.f - z) * hh;
                out[(size_t)row * DD + j] = o;
            }
        }
    }
}

// ---------------------------------------------------------------------------
extern "C" void kernel_launch(void* const* d_in, const int* in_sizes, int n_in,
                              void* d_out, int out_size, void* d_ws, size_t ws_size,
                              hipStream_t stream) {
    const float* atom_state = (const float*)d_in[0];
    const float* messages   = (const float*)d_in[1];
    const int*   conn       = (const int*)d_in[2];
    const float* w0         = (const float*)d_in[3];
    const float* w1         = (const float*)d_in[4];
    const float* bias       = (const float*)d_in[5];
    float* out = (float*)d_out;

    __bf16* agg    = (__bf16*)d_ws;
    __bf16* wt     = (__bf16*)((char*)d_ws + WT_OFF);
    int*    counts = (int*)((char*)d_ws + CNT_OFF);
    int*    bucket = (int*)((char*)d_ws + BKT_OFF);

    hipMemsetAsync(counts, 0, CNT_BYTES, stream);
    transpose_weights<<<(2 * THREE_D * DD) / 256, 256, 0, stream>>>(w0, w1, wt);
    scatter_ids<<<(BB * EE) / 256, 256, 0, stream>>>(conn, counts, bucket);
    gather_messages<<<MM / 4, 256, 0, stream>>>(messages, counts, bucket, agg);
    gru_gemm<<<MM / 128, 256, 0, stream>>>(agg, atom_state, wt, bias, out);
}